// Round 12
// baseline (121.317 us; speedup 1.0000x reference)
//
#include <hip/hip_runtime.h>

#define RCUT 6.0f
// ===== PROBE ROUND: work amplification for rocprof visibility =====
#define EMBED_REP 8
#define FIT_REP   16

typedef _Float16 h2v __attribute__((ext_vector_type(2)));
typedef _Float16 h8  __attribute__((ext_vector_type(8)));
typedef float    f4  __attribute__((ext_vector_type(4)));

__device__ __forceinline__ float fast_tanh(float x) {
    float e = __expf(2.0f * x);              // inf for large x -> tanh=1
    return 1.0f - 2.0f * __builtin_amdgcn_rcpf(e + 1.0f);
}

__device__ __forceinline__ h2v pkh(float a, float b) {
#if __has_builtin(__builtin_amdgcn_cvt_pkrtz)
    union { __fp16 __attribute__((ext_vector_type(2))) r; h2v h; } u;
    u.r = __builtin_amdgcn_cvt_pkrtz(a, b);
    return u.h;
#else
    h2v r; r.x = (_Float16)a; r.y = (_Float16)b; return r;
#endif
}

// ---- Kernel 1: identical to R11 except tile loop repeated EMBED_REP x ------
__global__ __launch_bounds__(256, 2) void k_embed(
    const float* __restrict__ coord, const float* __restrict__ box,
    const float* __restrict__ srmean, const float* __restrict__ srstd,
    const float* __restrict__ xrsrstd, const float* __restrict__ Gbias,
    const float* __restrict__ eW0, const float* __restrict__ eb0,
    const float* __restrict__ eW1, const float* __restrict__ eb1,
    const float* __restrict__ eW2, const float* __restrict__ eb2,
    const int* __restrict__ n1p,
    const float* __restrict__ fW0, const float* __restrict__ fW1,
    h2v* __restrict__ feat, _Float16* __restrict__ W0ht,
    _Float16* __restrict__ W1ht, unsigned int* __restrict__ counter, int N)
{
    const int nb  = blockIdx.x;
    const int tid = threadIdx.x;
    const int NB  = N >> 1;

    __shared__ float s_w0[2][16], s_b0[2][16];
    __shared__ __align__(16) _Float16 s_srn[1024];
    __shared__ __align__(16) _Float16 s_cf[4][1024];
    __shared__ __align__(16) _Float16 s_h1[128][32];
    __shared__ __align__(16) _Float16 s_ef[4][4][64][8];
    __shared__ unsigned short s_nbr[1024];
    __shared__ float s_g4[2][256];
    __shared__ __align__(16) _Float16 w1t[2][32][24];
    __shared__ __align__(16) _Float16 w2t[2][64][40];
    __shared__ int s_wA[4], s_wB[4];

    if (nb >= NB) {
        const int b = nb - NB;
        if (b == 0 && tid == 0) *counter = 0u;
        float (*s_t)[33] = reinterpret_cast<float(*)[33]>(&s_ef[0][0][0][0]);
        if (b < 256) {
            int type = b >> 7, tb = b & 127;
            int ki = tb >> 2, ci = tb & 3;
            const float* src = fW0 + (size_t)type * 131072;
            int c = tid & 31, r0 = (tid >> 5) * 4;
            #pragma unroll
            for (int q = 0; q < 4; q++)
                s_t[r0 + q][c] = src[(size_t)(ki * 32 + r0 + q) * 128 + ci * 32 + c];
            __syncthreads();
            _Float16* dst = W0ht + (size_t)type * 131072;
            int kk = tid & 31, c0 = (tid >> 5) * 4;
            #pragma unroll
            for (int q = 0; q < 4; q++)
                dst[(size_t)(ci * 32 + c0 + q) * 1024 + ki * 32 + kk] = (_Float16)s_t[kk][c0 + q];
        } else {
            int b2v = b - 256, type = b2v >> 4, tb = b2v & 15;
            int ki = tb >> 2, ci = tb & 3;
            const float* src = fW1 + (size_t)type * 16384;
            int c = tid & 31, r0 = (tid >> 5) * 4;
            #pragma unroll
            for (int q = 0; q < 4; q++)
                s_t[r0 + q][c] = src[(size_t)(ki * 32 + r0 + q) * 128 + ci * 32 + c];
            __syncthreads();
            _Float16* dst = W1ht + (size_t)type * 16384;
            int kk = tid & 31, c0 = (tid >> 5) * 4;
            #pragma unroll
            for (int q = 0; q < 4; q++)
                dst[(size_t)(ci * 32 + c0 + q) * 128 + ki * 32 + kk] = (_Float16)s_t[kk][c0 + q];
        }
        return;
    }

    const int nA = 2 * nb, nBt = 2 * nb + 1;
    const int n1 = *n1p;
    const int ti = (nA >= n1) ? 1 : 0;
    const int wid = tid >> 6, lane = tid & 63;
    const int l15 = lane & 15, lk = lane >> 4;

    for (int t = tid; t < 32; t += 256) { int j = t >> 4, f = t & 15;
        s_w0[j][f] = eW0[(2 * ti + j) * 16 + f];
        s_b0[j][f] = eb0[(2 * ti + j) * 16 + f]; }
    for (int idx = tid; idx < 1024; idx += 256) {
        int j = idx >> 9, r = idx & 511, f = r >> 5, g = r & 31;
        w1t[j][g][f] = (_Float16)eW1[(2 * ti + j) * 512 + f * 32 + g];
    }
    for (int idx = tid; idx < 4096; idx += 256) {
        int j = idx >> 11, r = idx & 2047, g = r >> 6, c = r & 63;
        w2t[j][c][g] = (_Float16)eW2[(2 * ti + j) * 2048 + g * 64 + c];
    }
    float b1r[2][2], b2r[2][4];
    #pragma unroll
    for (int j = 0; j < 2; j++) {
        #pragma unroll
        for (int q = 0; q < 2; q++) b1r[j][q] = eb1[(2 * ti + j) * 32 + 16 * q + l15];
        #pragma unroll
        for (int q = 0; q < 4; q++) b2r[j][q] = eb2[(2 * ti + j) * 64 + 16 * q + l15];
    }

    const float Lx = box[0], Ly = box[4], Lz = box[8];
    const float iLx = 1.0f / Lx, iLy = 1.0f / Ly, iLz = 1.0f / Lz;
    const float xA = coord[nA], yA = coord[N + nA], zA = coord[2 * N + nA];
    const float xB = coord[nBt], yB = coord[N + nBt], zB = coord[2 * N + nBt];
    const float srm  = srmean[ti];
    const float isrs = 1.0f / srstd[ti];
    const float ixrs = 1.0f / xrsrstd[ti];

    unsigned long long balA[4], balB[4];
    {
        int wA = 0, wB = 0;
        const int mystart = wid * 256;
        #pragma unroll
        for (int r = 0; r < 4; r++) {
            int m = mystart + r * 64 + lane;
            float x = coord[m], y = coord[N + m], z = coord[2 * N + m];
            float ax = x - xA; ax -= Lx * rintf(ax * iLx);
            float ay = y - yA; ay -= Ly * rintf(ay * iLy);
            float az = z - zA; az -= Lz * rintf(az * iLz);
            float ra = ax * ax + ay * ay + az * az;
            float bx = x - xB; bx -= Lx * rintf(bx * iLx);
            float by = y - yB; by -= Ly * rintf(by * iLy);
            float bz = z - zB; bz -= Lz * rintf(bz * iLz);
            float rb = bx * bx + by * by + bz * bz;
            bool pA = (ra < RCUT * RCUT) && (m != nA);
            bool pB = (rb < RCUT * RCUT) && (m != nBt);
            balA[r] = __ballot(pA);
            balB[r] = __ballot(pB);
            wA += (int)__popcll(balA[r]);
            wB += (int)__popcll(balB[r]);
        }
        if (lane == 0) { s_wA[wid] = wA; s_wB[wid] = wB; }
    }
    __syncthreads();
    int cntA = s_wA[0] + s_wA[1] + s_wA[2] + s_wA[3];
    int cntB = s_wB[0] + s_wB[1] + s_wB[2] + s_wB[3];
    int cnt  = cntA + cntB;
    if (cnt > 1024) cnt = 1024;
    if (cntA > 1024) cntA = 1024;
    {
        int baseA = 0, baseB = cntA;
        for (int w = 0; w < wid; w++) { baseA += s_wA[w]; baseB += s_wB[w]; }
        const unsigned long long lt = (1ull << lane) - 1ull;
        const int mystart = wid * 256;
        #pragma unroll
        for (int r = 0; r < 4; r++) {
            int m = mystart + r * 64 + lane;
            float x = coord[m], y = coord[N + m], z = coord[2 * N + m];
            #pragma unroll
            for (int cc = 0; cc < 2; cc++) {
                unsigned long long bal = cc ? balB[r] : balA[r];
                int base = cc ? baseB : baseA;
                if ((bal >> lane) & 1ull) {
                    int pos = base + (int)__popcll(bal & lt);
                    if (pos < 1024) {
                        float dx = x - (cc ? xB : xA); dx -= Lx * rintf(dx * iLx);
                        float dy = y - (cc ? yB : yA); dy -= Ly * rintf(dy * iLy);
                        float dz = z - (cc ? zB : zA); dz -= Lz * rintf(dz * iLz);
                        float r2 = dx * dx + dy * dy + dz * dz;
                        float rr = sqrtf(r2);
                        float rinv = __builtin_amdgcn_rcpf(rr);
                        float u  = rr * (1.0f / RCUT);
                        float u3 = u * u * u;
                        float sw_ = ((-6.0f * u + 15.0f) * u - 10.0f) * u3 + 1.0f;
                        float sr  = sw_ * rinv;
                        float crs = sr * rinv * ixrs + 1e-15f;
                        s_srn[pos]   = (_Float16)((sr - srm) * isrs);
                        s_cf[0][pos] = (_Float16)(sr * isrs);
                        s_cf[1][pos] = (_Float16)(crs * dx);
                        s_cf[2][pos] = (_Float16)(crs * dy);
                        s_cf[3][pos] = (_Float16)(crs * dz);
                        s_nbr[pos]   = (unsigned short)m;
                    }
                }
                if (cc) baseB += (int)__popcll(bal);
                else    baseA += (int)__popcll(bal);
            }
        }
    }
    __syncthreads();
    const int ntiles = (cnt + 127) >> 7;
    for (int i = cnt + tid; i < ntiles * 128; i += 256) {
        s_srn[i] = (_Float16)0.0f; s_nbr[i] = 0;
        s_cf[0][i] = (_Float16)0.0f; s_cf[1][i] = (_Float16)0.0f;
        s_cf[2][i] = (_Float16)0.0f; s_cf[3][i] = (_Float16)0.0f;
    }
    __syncthreads();

    f4 gacc = {0.0f, 0.0f, 0.0f, 0.0f};
    const f4 zf4 = {0.0f, 0.0f, 0.0f, 0.0f};

    // ===== PROBE: repeat the whole tile loop EMBED_REP times (identical math;
    // gacc accumulates EMBED_REP copies, scaled out in the epilogue) =====
    for (int rep = 0; rep < EMBED_REP; rep++) {
    for (int t = 0; t < ntiles; t++) {
        const int t128 = t << 7;
        __syncthreads();   // B1

        #pragma unroll
        for (int mt2 = 0; mt2 < 2; mt2++) {
            const int mt = 2 * wid + mt2;
            const int row = 16 * mt + l15;
            const int rp = t128 + row;
            float srn = (float)s_srn[rp];
            int jr = (s_nbr[rp] >= n1) ? 1 : 0;
            h8 a = {};
            if (lk < 2) {
                const float* wp = &s_w0[jr][8 * lk];
                const float* bp = &s_b0[jr][8 * lk];
                #pragma unroll
                for (int q = 0; q < 8; q++)
                    a[q] = (_Float16)fast_tanh(fmaf(srn, wp[q], bp[q]));
            }
            #pragma unroll
            for (int nt1 = 0; nt1 < 2; nt1++) {
                const int c = 16 * nt1 + l15;
                h8 b0f = {}, b1f = {};
                if (lk < 2) {
                    b0f = *(const h8*)&w1t[0][c][8 * lk];
                    b1f = *(const h8*)&w1t[1][c][8 * lk];
                }
                f4 d0 = __builtin_amdgcn_mfma_f32_16x16x32_f16(a, b0f, zf4, 0, 0, 0);
                f4 d1 = __builtin_amdgcn_mfma_f32_16x16x32_f16(a, b1f, zf4, 0, 0, 0);
                #pragma unroll
                for (int r = 0; r < 4; r++) {
                    int gp = 16 * mt + 4 * lk + r;
                    bool is0 = (s_nbr[t128 + gp] < n1);
                    float hv = fast_tanh((is0 ? d0[r] : d1[r]) + (is0 ? b1r[0][nt1] : b1r[1][nt1]));
                    int e = 16 * nt1 + l15;
                    s_h1[gp][(((e >> 3) ^ ((gp >> 1) & 3)) << 3) + (e & 7)] = (_Float16)hv;
                }
            }
        }
        asm volatile("" ::: "memory");
        #pragma unroll
        for (int mt2 = 0; mt2 < 2; mt2++) {
            const int mt = 2 * wid + mt2;
            const int row = 16 * mt + l15;
            h8 a2 = *(const h8*)&s_h1[row][((lk ^ ((row >> 1) & 3)) << 3)];
            #pragma unroll
            for (int nt = 0; nt < 4; nt++) {
                const int c = 16 * nt + l15;
                h8 w20 = *(const h8*)&w2t[0][c][8 * lk];
                h8 w21 = *(const h8*)&w2t[1][c][8 * lk];
                f4 e0 = __builtin_amdgcn_mfma_f32_16x16x32_f16(a2, w20, zf4, 0, 0, 0);
                f4 e1 = __builtin_amdgcn_mfma_f32_16x16x32_f16(a2, w21, zf4, 0, 0, 0);
                #pragma unroll
                for (int r = 0; r < 4; r++) {
                    int gp = 16 * mt + 4 * lk + r;
                    bool is0 = (s_nbr[t128 + gp] < n1);
                    float ev = fast_tanh((is0 ? e0[r] : e1[r]) + (is0 ? b2r[0][nt] : b2r[1][nt]));
                    s_ef[nt][gp >> 5][l15 + 16 * ((gp & 31) >> 3)][gp & 7] = (_Float16)ev;
                }
            }
        }
        __syncthreads();   // B3

        #pragma unroll
        for (int ks = 0; ks < 4; ks++) {
            const int s = t128 + 32 * ks;
            h8 ac = {};
            if (l15 < 8) {
                const bool rowA = l15 < 4;
                const int  cr   = rowA ? l15 : (l15 - 4);
                const bool allA = (s + 31) < cntA;
                const bool allB = s >= cntA;
                if ((allA && rowA) || (allB && !rowA)) {
                    ac = *(const h8*)&s_cf[cr][s + 8 * lk];
                } else if (!allA && !allB) {
                    #pragma unroll
                    for (int r = 0; r < 8; r++) {
                        int p = s + 8 * lk + r;
                        bool isA = p < cntA;
                        if (isA == rowA) ac[r] = s_cf[cr][p];
                    }
                }
            }
            h8 eb = *(const h8*)&s_ef[wid][ks][lane][0];
            gacc = __builtin_amdgcn_mfma_f32_16x16x32_f16(ac, eb, gacc, 0, 0, 0);
        }
    }
    }   // rep

    if (lk < 2) {
        float* sg = &s_g4[lk][0];
        #pragma unroll
        for (int r = 0; r < 4; r++) {
            float gv = gacc[r] * (1.0f / (64.0f * (float)EMBED_REP));
            if (r == 0) gv += Gbias[16 * wid + l15];
            sg[r * 64 + 16 * wid + l15] = gv;
        }
    }
    __syncthreads();
    #pragma unroll
    for (int at = 0; at < 2; at++) {
        const float* sg = &s_g4[at][0];
        h2v* outp = feat + (size_t)(2 * nb + at) * 512;
        #pragma unroll
        for (int q = 0; q < 2; q++) {
            int o2 = tid + 256 * q;
            int a = o2 >> 5, c = (2 * o2) & 63;
            float ga0 = sg[a],       ga1 = sg[64 + a];
            float ga2 = sg[128 + a], ga3 = sg[192 + a];
            float s0 = ga0 * sg[c];
            s0 = fmaf(ga1, sg[64 + c],  s0);
            s0 = fmaf(ga2, sg[128 + c], s0);
            s0 = fmaf(ga3, sg[192 + c], s0);
            float s1 = ga0 * sg[c + 1];
            s1 = fmaf(ga1, sg[64 + c + 1],  s1);
            s1 = fmaf(ga2, sg[128 + c + 1], s1);
            s1 = fmaf(ga3, sg[192 + c + 1], s1);
            outp[o2] = pkh(s0, s1);
        }
    }
}

// ---- Kernel 2: identical to R11 except MFMA loops repeated FIT_REP x -------
__global__ __launch_bounds__(512) void k_fit(
    const _Float16* __restrict__ featf, const _Float16* __restrict__ W0ht,
    const _Float16* __restrict__ W1ht,
    const float* __restrict__ b0, const float* __restrict__ b1,
    const float* __restrict__ W2, const float* __restrict__ b2,
    const float* __restrict__ Ebias, const int* __restrict__ n1p,
    unsigned int* __restrict__ counter, float* __restrict__ slots,
    float* __restrict__ out)
{
    __shared__ float s_red[4][2][16][64];
    __shared__ __align__(16) _Float16 s_hd[16][128];
    __shared__ float s_sum[16][32];

    const int tid = threadIdx.x;
    const int lane = tid & 63, w = tid >> 6;
    const int kq = w >> 1, ch = w & 1;
    const int l15 = lane & 15, lk = lane >> 4;
    const int n0 = blockIdx.x * 16;
    const int ia = (n0 >= *n1p) ? 1 : 0;
    const f4 zf4 = {0.0f, 0.0f, 0.0f, 0.0f};
    const float invrep = 1.0f / (float)FIT_REP;

    const _Float16* Ap = featf + (size_t)(n0 + l15) * 1024 + kq * 256;
    const _Float16* B0 = W0ht + (size_t)ia * 131072 + kq * 256;
    f4 acc[4] = {zf4, zf4, zf4, zf4};
    for (int rep = 0; rep < FIT_REP; rep++) {
        #pragma unroll
        for (int ks = 0; ks < 8; ks++) {
            h8 a = *(const h8*)(Ap + ks * 32 + 8 * lk);
            #pragma unroll
            for (int nt = 0; nt < 4; nt++) {
                const int c = ch * 64 + nt * 16 + l15;
                h8 b = *(const h8*)(B0 + (size_t)c * 1024 + ks * 32 + 8 * lk);
                acc[nt] = __builtin_amdgcn_mfma_f32_16x16x32_f16(a, b, acc[nt], 0, 0, 0);
            }
        }
    }
    #pragma unroll
    for (int nt = 0; nt < 4; nt++)
        #pragma unroll
        for (int r = 0; r < 4; r++)
            s_red[kq][ch][4 * lk + r][nt * 16 + l15] = acc[nt][r] * invrep;
    __syncthreads();

    {
        const int row = tid >> 5, c0 = (tid & 31) * 4;
        const int chh = c0 >> 6, cl = c0 & 63;
        f4 v = *(const f4*)&s_red[0][chh][row][cl];
        v += *(const f4*)&s_red[1][chh][row][cl];
        v += *(const f4*)&s_red[2][chh][row][cl];
        v += *(const f4*)&s_red[3][chh][row][cl];
        #pragma unroll
        for (int q = 0; q < 4; q++) {
            int c = c0 + q;
            float h = fast_tanh(v[q] + b0[ia * 128 + c]);
            s_hd[row][(((c >> 3) ^ row) << 3) + (c & 7)] = (_Float16)h;
        }
    }
    __syncthreads();

    f4 acc1[4] = {zf4, zf4, zf4, zf4};
    {
        h8 a = *(const h8*)&s_hd[l15][(((4 * kq + lk) ^ l15) & 15) << 3];
        const _Float16* B1 = W1ht + (size_t)ia * 16384 + kq * 32;
        for (int rep = 0; rep < FIT_REP; rep++) {
            #pragma unroll
            for (int nt = 0; nt < 4; nt++) {
                const int c = ch * 64 + nt * 16 + l15;
                h8 b = *(const h8*)(B1 + (size_t)c * 128 + 8 * lk);
                acc1[nt] = __builtin_amdgcn_mfma_f32_16x16x32_f16(a, b, acc1[nt], 0, 0, 0);
            }
        }
    }
    #pragma unroll
    for (int nt = 0; nt < 4; nt++)
        #pragma unroll
        for (int r = 0; r < 4; r++)
            s_red[kq][ch][4 * lk + r][nt * 16 + l15] = acc1[nt][r] * invrep;
    __syncthreads();

    {
        const int row = tid >> 5, c0 = (tid & 31) * 4;
        const int chh = c0 >> 6, cl = c0 & 63;
        f4 v = *(const f4*)&s_red[0][chh][row][cl];
        v += *(const f4*)&s_red[1][chh][row][cl];
        v += *(const f4*)&s_red[2][chh][row][cl];
        v += *(const f4*)&s_red[3][chh][row][cl];
        float pv = 0.0f;
        #pragma unroll
        for (int q = 0; q < 4; q++) {
            int c = c0 + q;
            pv += fast_tanh(v[q] + b1[ia * 128 + c]) * W2[ia * 128 + c];
        }
        s_sum[row][tid & 31] = pv;
    }
    __syncthreads();
    if (w == 0) {
        const int row = lane >> 2, g = lane & 3;
        float s = 0.0f;
        #pragma unroll
        for (int i = 0; i < 8; i++) s += s_sum[row][8 * g + i];
        s += __shfl_xor(s, 1);  s += __shfl_xor(s, 2);
        s += __shfl_xor(s, 4);  s += __shfl_xor(s, 8);
        s += __shfl_xor(s, 16); s += __shfl_xor(s, 32);
        if (lane == 0) {
            float e = s + 16.0f * (b2[ia] + Ebias[ia]);
            slots[blockIdx.x] = e;
            __threadfence();
            unsigned int old = atomicAdd(counter, 1u);
            if (old == 63u) {
                __threadfence();
                float tot = 0.0f;
                for (int i = 0; i < 64; i++)
                    tot += __hip_atomic_load(&slots[i], __ATOMIC_RELAXED, __HIP_MEMORY_SCOPE_AGENT);
                out[0] = tot;
            }
        }
    }
}

extern "C" void kernel_launch(void* const* d_in, const int* in_sizes, int n_in,
                              void* d_out, int out_size, void* d_ws, size_t ws_size,
                              hipStream_t stream) {
    const float* coord   = (const float*)d_in[0];
    const float* box     = (const float*)d_in[1];
    const float* srmean  = (const float*)d_in[2];
    const float* srstd   = (const float*)d_in[3];
    const float* xrsrstd = (const float*)d_in[4];
    const float* Gbias   = (const float*)d_in[5];
    const float* Ebias   = (const float*)d_in[6];
    const float* eW0     = (const float*)d_in[7];
    const float* eb0     = (const float*)d_in[8];
    const float* eW1     = (const float*)d_in[9];
    const float* eb1     = (const float*)d_in[10];
    const float* eW2     = (const float*)d_in[11];
    const float* eb2     = (const float*)d_in[12];
    const float* fW0     = (const float*)d_in[13];
    const float* fb0     = (const float*)d_in[14];
    const float* fW1     = (const float*)d_in[15];
    const float* fb1     = (const float*)d_in[16];
    const float* fW2     = (const float*)d_in[17];
    const float* fb2     = (const float*)d_in[18];
    const int*   n1p     = (const int*)d_in[19];

    const int N = in_sizes[0] / 3;          // 1024
    h2v*      featbuf = (h2v*)d_ws;                                       // 2 MB
    _Float16* W0ht = (_Float16*)((char*)d_ws + (size_t)2 * 1024 * 1024);  // 512 KB
    _Float16* W1ht = W0ht + 2 * 131072;                                   // 64 KB
    char* tail = (char*)d_ws + (size_t)(2 * 1024 + 512 + 64) * 1024;
    unsigned int* counter = (unsigned int*)tail;
    float*        slots   = (float*)(tail + 64);

    k_embed<<<N / 2 + 288, 256, 0, stream>>>(coord, box, srmean, srstd, xrsrstd,
                                             Gbias, eW0, eb0, eW1, eb1, eW2, eb2,
                                             n1p, fW0, fW1, featbuf, W0ht, W1ht,
                                             counter, N);
    k_fit<<<N / 16, 512, 0, stream>>>((const _Float16*)featbuf, W0ht, W1ht,
                                      fb0, fb1, fW2, fb2, Ebias, n1p,
                                      counter, slots, (float*)d_out);
}

// Round 13
// 46.102 us; speedup vs baseline: 2.6315x; 2.6315x over previous
//
#include <hip/hip_runtime.h>

#define RCUT 6.0f
#define NPREP 288

typedef _Float16 h2v __attribute__((ext_vector_type(2)));
typedef _Float16 h8  __attribute__((ext_vector_type(8)));
typedef float    f4  __attribute__((ext_vector_type(4)));

// Pade(5,4) tanh: rel err <= ~5e-4, single rcp (no exp). Clamped to [-1,1].
__device__ __forceinline__ float fast_tanh(float x) {
    float x2 = x * x;
    float num = x * fmaf(x2, fmaf(x2, 1.0f, 105.0f), 945.0f);
    float den = fmaf(x2, fmaf(x2, 15.0f, 420.0f), 945.0f);
    float r = num * __builtin_amdgcn_rcpf(den);
    return fminf(fmaxf(r, -1.0f), 1.0f);
}

__device__ __forceinline__ h2v pkh(float a, float b) {
#if __has_builtin(__builtin_amdgcn_cvt_pkrtz)
    union { __fp16 __attribute__((ext_vector_type(2))) r; h2v h; } u;
    u.r = __builtin_amdgcn_cvt_pkrtz(a, b);
    return u.h;
#else
    h2v r; r.x = (_Float16)a; r.y = (_Float16)b; return r;
#endif
}

// ---- Kernel 1: blocks [0,NPREP) = fit-weight prep (run FIRST, overlapped);
//      blocks [NPREP, NPREP+512) = atom pairs -------------------------------
__global__ __launch_bounds__(256, 2) void k_embed(
    const float* __restrict__ coord, const float* __restrict__ box,
    const float* __restrict__ srmean, const float* __restrict__ srstd,
    const float* __restrict__ xrsrstd, const float* __restrict__ Gbias,
    const float* __restrict__ eW0, const float* __restrict__ eb0,
    const float* __restrict__ eW1, const float* __restrict__ eb1,
    const float* __restrict__ eW2, const float* __restrict__ eb2,
    const int* __restrict__ n1p,
    const float* __restrict__ fW0, const float* __restrict__ fW1,
    h2v* __restrict__ feat, _Float16* __restrict__ W0ht,
    _Float16* __restrict__ W1ht, unsigned int* __restrict__ counter, int N)
{
    const int tid = threadIdx.x;

    __shared__ float s_w0[2][16], s_b0[2][16];
    __shared__ __align__(16) _Float16 s_srn[1024];
    __shared__ __align__(16) _Float16 s_cf[4][1024];
    __shared__ __align__(16) _Float16 s_h1[128][32];
    __shared__ __align__(16) _Float16 s_ef[4][4][64][8];
    __shared__ unsigned short s_nbr[1024];
    __shared__ float s_g4[2][256];
    __shared__ __align__(16) _Float16 w1t[2][32][24];
    __shared__ __align__(16) _Float16 w2t[2][64][40];
    __shared__ int s_wA[4], s_wB[4];

    // ================= prep path (scheduled first) ===========================
    if (blockIdx.x < NPREP) {
        const int b = blockIdx.x;
        if (b == 0 && tid == 0) *counter = 0u;
        float (*s_t)[33] = reinterpret_cast<float(*)[33]>(&s_ef[0][0][0][0]);
        if (b < 256) {
            int type = b >> 7, tb = b & 127;
            int ki = tb >> 2, ci = tb & 3;
            const float* src = fW0 + (size_t)type * 131072;
            int c = tid & 31, r0 = (tid >> 5) * 4;
            #pragma unroll
            for (int q = 0; q < 4; q++)
                s_t[r0 + q][c] = src[(size_t)(ki * 32 + r0 + q) * 128 + ci * 32 + c];
            __syncthreads();
            _Float16* dst = W0ht + (size_t)type * 131072;
            int kk = tid & 31, c0 = (tid >> 5) * 4;
            #pragma unroll
            for (int q = 0; q < 4; q++)
                dst[(size_t)(ci * 32 + c0 + q) * 1024 + ki * 32 + kk] = (_Float16)s_t[kk][c0 + q];
        } else {
            int b2v = b - 256, type = b2v >> 4, tb = b2v & 15;
            int ki = tb >> 2, ci = tb & 3;
            const float* src = fW1 + (size_t)type * 16384;
            int c = tid & 31, r0 = (tid >> 5) * 4;
            #pragma unroll
            for (int q = 0; q < 4; q++)
                s_t[r0 + q][c] = src[(size_t)(ki * 32 + r0 + q) * 128 + ci * 32 + c];
            __syncthreads();
            _Float16* dst = W1ht + (size_t)type * 16384;
            int kk = tid & 31, c0 = (tid >> 5) * 4;
            #pragma unroll
            for (int q = 0; q < 4; q++)
                dst[(size_t)(ci * 32 + c0 + q) * 128 + ki * 32 + kk] = (_Float16)s_t[kk][c0 + q];
        }
        return;
    }

    // ================= main path =================
    const int nb  = blockIdx.x - NPREP;
    const int nA = 2 * nb, nBt = 2 * nb + 1;
    const int n1 = *n1p;
    const int ti = (nA >= n1) ? 1 : 0;
    const int wid = tid >> 6, lane = tid & 63;
    const int l15 = lane & 15, lk = lane >> 4;

    // ---- coalesced weight staging into LDS ----
    for (int t = tid; t < 32; t += 256) { int j = t >> 4, f = t & 15;
        s_w0[j][f] = eW0[(2 * ti + j) * 16 + f];
        s_b0[j][f] = eb0[(2 * ti + j) * 16 + f]; }
    for (int idx = tid; idx < 1024; idx += 256) {        // W1: [j][g(c)][f(k)]
        int j = idx >> 9, r = idx & 511, f = r >> 5, g = r & 31;
        w1t[j][g][f] = (_Float16)eW1[(2 * ti + j) * 512 + f * 32 + g];
    }
    for (int idx = tid; idx < 4096; idx += 256) {        // W2: [j][c][g(k)]
        int j = idx >> 11, r = idx & 2047, g = r >> 6, c = r & 63;
        w2t[j][c][g] = (_Float16)eW2[(2 * ti + j) * 2048 + g * 64 + c];
    }
    float b1r[2][2], b2r[2][4];
    #pragma unroll
    for (int j = 0; j < 2; j++) {
        #pragma unroll
        for (int q = 0; q < 2; q++) b1r[j][q] = eb1[(2 * ti + j) * 32 + 16 * q + l15];
        #pragma unroll
        for (int q = 0; q < 4; q++) b2r[j][q] = eb2[(2 * ti + j) * 64 + 16 * q + l15];
    }

    const float Lx = box[0], Ly = box[4], Lz = box[8];
    const float iLx = 1.0f / Lx, iLy = 1.0f / Ly, iLz = 1.0f / Lz;
    const float xA = coord[nA], yA = coord[N + nA], zA = coord[2 * N + nA];
    const float xB = coord[nBt], yB = coord[N + nBt], zB = coord[2 * N + nBt];
    const float srm  = srmean[ti];
    const float isrs = 1.0f / srstd[ti];
    const float ixrs = 1.0f / xrsrstd[ti];

    // ---- dual-center scan: pass 1 = ballots only ----
    unsigned long long balA[4], balB[4];
    {
        int wA = 0, wB = 0;
        const int mystart = wid * 256;
        #pragma unroll
        for (int r = 0; r < 4; r++) {
            int m = mystart + r * 64 + lane;
            float x = coord[m], y = coord[N + m], z = coord[2 * N + m];
            float ax = x - xA; ax -= Lx * rintf(ax * iLx);
            float ay = y - yA; ay -= Ly * rintf(ay * iLy);
            float az = z - zA; az -= Lz * rintf(az * iLz);
            float ra = ax * ax + ay * ay + az * az;
            float bx = x - xB; bx -= Lx * rintf(bx * iLx);
            float by = y - yB; by -= Ly * rintf(by * iLy);
            float bz = z - zB; bz -= Lz * rintf(bz * iLz);
            float rb = bx * bx + by * by + bz * bz;
            bool pA = (ra < RCUT * RCUT) && (m != nA);
            bool pB = (rb < RCUT * RCUT) && (m != nBt);
            balA[r] = __ballot(pA);
            balB[r] = __ballot(pB);
            wA += (int)__popcll(balA[r]);
            wB += (int)__popcll(balB[r]);
        }
        if (lane == 0) { s_wA[wid] = wA; s_wB[wid] = wB; }
    }
    __syncthreads();
    int cntA = s_wA[0] + s_wA[1] + s_wA[2] + s_wA[3];
    int cntB = s_wB[0] + s_wB[1] + s_wB[2] + s_wB[3];
    int cnt  = cntA + cntB;
    if (cnt > 1024) cnt = 1024;
    if (cntA > 1024) cntA = 1024;
    {
        int baseA = 0, baseB = cntA;
        for (int w = 0; w < wid; w++) { baseA += s_wA[w]; baseB += s_wB[w]; }
        const unsigned long long lt = (1ull << lane) - 1ull;
        const int mystart = wid * 256;
        #pragma unroll
        for (int r = 0; r < 4; r++) {
            int m = mystart + r * 64 + lane;
            float x = coord[m], y = coord[N + m], z = coord[2 * N + m];
            #pragma unroll
            for (int cc = 0; cc < 2; cc++) {
                unsigned long long bal = cc ? balB[r] : balA[r];
                int base = cc ? baseB : baseA;
                if ((bal >> lane) & 1ull) {
                    int pos = base + (int)__popcll(bal & lt);
                    if (pos < 1024) {
                        float dx = x - (cc ? xB : xA); dx -= Lx * rintf(dx * iLx);
                        float dy = y - (cc ? yB : yA); dy -= Ly * rintf(dy * iLy);
                        float dz = z - (cc ? zB : zA); dz -= Lz * rintf(dz * iLz);
                        float r2 = dx * dx + dy * dy + dz * dz;
                        float rr = sqrtf(r2);
                        float rinv = __builtin_amdgcn_rcpf(rr);
                        float u  = rr * (1.0f / RCUT);
                        float u3 = u * u * u;
                        float sw_ = ((-6.0f * u + 15.0f) * u - 10.0f) * u3 + 1.0f;
                        float sr  = sw_ * rinv;
                        float crs = sr * rinv * ixrs + 1e-15f;
                        s_srn[pos]   = (_Float16)((sr - srm) * isrs);
                        s_cf[0][pos] = (_Float16)(sr * isrs);
                        s_cf[1][pos] = (_Float16)(crs * dx);
                        s_cf[2][pos] = (_Float16)(crs * dy);
                        s_cf[3][pos] = (_Float16)(crs * dz);
                        s_nbr[pos]   = (unsigned short)m;
                    }
                }
                if (cc) baseB += (int)__popcll(bal);
                else    baseA += (int)__popcll(bal);
            }
        }
    }
    __syncthreads();
    const int ntiles = (cnt + 127) >> 7;
    for (int i = cnt + tid; i < ntiles * 128; i += 256) {
        s_srn[i] = (_Float16)0.0f; s_nbr[i] = 0;
        s_cf[0][i] = (_Float16)0.0f; s_cf[1][i] = (_Float16)0.0f;
        s_cf[2][i] = (_Float16)0.0f; s_cf[3][i] = (_Float16)0.0f;
    }
    __syncthreads();

    f4 gacc = {0.0f, 0.0f, 0.0f, 0.0f};
    const f4 zf4 = {0.0f, 0.0f, 0.0f, 0.0f};

    for (int t = 0; t < ntiles; t++) {
        const int t128 = t << 7;
        __syncthreads();   // B1

        #pragma unroll
        for (int mt2 = 0; mt2 < 2; mt2++) {
            const int mt = 2 * wid + mt2;
            const int row = 16 * mt + l15;
            const int rp = t128 + row;
            float srn = (float)s_srn[rp];
            int jr = (s_nbr[rp] >= n1) ? 1 : 0;
            h8 a = {};
            if (lk < 2) {
                const float* wp = &s_w0[jr][8 * lk];
                const float* bp = &s_b0[jr][8 * lk];
                #pragma unroll
                for (int q = 0; q < 8; q++)
                    a[q] = (_Float16)fast_tanh(fmaf(srn, wp[q], bp[q]));
            }
            #pragma unroll
            for (int nt1 = 0; nt1 < 2; nt1++) {
                const int c = 16 * nt1 + l15;
                h8 b0f = {}, b1f = {};
                if (lk < 2) {
                    b0f = *(const h8*)&w1t[0][c][8 * lk];
                    b1f = *(const h8*)&w1t[1][c][8 * lk];
                }
                f4 d0 = __builtin_amdgcn_mfma_f32_16x16x32_f16(a, b0f, zf4, 0, 0, 0);
                f4 d1 = __builtin_amdgcn_mfma_f32_16x16x32_f16(a, b1f, zf4, 0, 0, 0);
                #pragma unroll
                for (int r = 0; r < 4; r++) {
                    int gp = 16 * mt + 4 * lk + r;
                    bool is0 = (s_nbr[t128 + gp] < n1);
                    float hv = fast_tanh((is0 ? d0[r] : d1[r]) + (is0 ? b1r[0][nt1] : b1r[1][nt1]));
                    int e = 16 * nt1 + l15;
                    s_h1[gp][(((e >> 3) ^ ((gp >> 1) & 3)) << 3) + (e & 7)] = (_Float16)hv;
                }
            }
        }
        asm volatile("" ::: "memory");
        #pragma unroll
        for (int mt2 = 0; mt2 < 2; mt2++) {
            const int mt = 2 * wid + mt2;
            const int row = 16 * mt + l15;
            h8 a2 = *(const h8*)&s_h1[row][((lk ^ ((row >> 1) & 3)) << 3)];
            #pragma unroll
            for (int nt = 0; nt < 4; nt++) {
                const int c = 16 * nt + l15;
                h8 w20 = *(const h8*)&w2t[0][c][8 * lk];
                h8 w21 = *(const h8*)&w2t[1][c][8 * lk];
                f4 e0 = __builtin_amdgcn_mfma_f32_16x16x32_f16(a2, w20, zf4, 0, 0, 0);
                f4 e1 = __builtin_amdgcn_mfma_f32_16x16x32_f16(a2, w21, zf4, 0, 0, 0);
                #pragma unroll
                for (int r = 0; r < 4; r++) {
                    int gp = 16 * mt + 4 * lk + r;
                    bool is0 = (s_nbr[t128 + gp] < n1);
                    float ev = fast_tanh((is0 ? e0[r] : e1[r]) + (is0 ? b2r[0][nt] : b2r[1][nt]));
                    s_ef[nt][gp >> 5][l15 + 16 * ((gp & 31) >> 3)][gp & 7] = (_Float16)ev;
                }
            }
        }
        __syncthreads();   // B3

        #pragma unroll
        for (int ks = 0; ks < 4; ks++) {
            const int s = t128 + 32 * ks;
            h8 ac = {};
            if (l15 < 8) {
                const bool rowA = l15 < 4;
                const int  cr   = rowA ? l15 : (l15 - 4);
                const bool allA = (s + 31) < cntA;
                const bool allB = s >= cntA;
                if ((allA && rowA) || (allB && !rowA)) {
                    ac = *(const h8*)&s_cf[cr][s + 8 * lk];
                } else if (!allA && !allB) {
                    #pragma unroll
                    for (int r = 0; r < 8; r++) {
                        int p = s + 8 * lk + r;
                        bool isA = p < cntA;
                        if (isA == rowA) ac[r] = s_cf[cr][p];
                    }
                }
            }
            h8 eb = *(const h8*)&s_ef[wid][ks][lane][0];
            gacc = __builtin_amdgcn_mfma_f32_16x16x32_f16(ac, eb, gacc, 0, 0, 0);
        }
    }

    if (lk < 2) {
        float* sg = &s_g4[lk][0];
        #pragma unroll
        for (int r = 0; r < 4; r++) {
            float gv = gacc[r] * (1.0f / 64.0f);
            if (r == 0) gv += Gbias[16 * wid + l15];
            sg[r * 64 + 16 * wid + l15] = gv;
        }
    }
    __syncthreads();
    #pragma unroll
    for (int at = 0; at < 2; at++) {
        const float* sg = &s_g4[at][0];
        h2v* outp = feat + (size_t)(2 * nb + at) * 512;
        #pragma unroll
        for (int q = 0; q < 2; q++) {
            int o2 = tid + 256 * q;
            int a = o2 >> 5, c = (2 * o2) & 63;
            float ga0 = sg[a],       ga1 = sg[64 + a];
            float ga2 = sg[128 + a], ga3 = sg[192 + a];
            float s0 = ga0 * sg[c];
            s0 = fmaf(ga1, sg[64 + c],  s0);
            s0 = fmaf(ga2, sg[128 + c], s0);
            s0 = fmaf(ga3, sg[192 + c], s0);
            float s1 = ga0 * sg[c + 1];
            s1 = fmaf(ga1, sg[64 + c + 1],  s1);
            s1 = fmaf(ga2, sg[128 + c + 1], s1);
            s1 = fmaf(ga3, sg[192 + c + 1], s1);
            outp[o2] = pkh(s0, s1);
        }
    }
}

// ---- Kernel 2: fit net, 128 blocks x 8 atoms, direct-from-L2 fragments ----
__global__ __launch_bounds__(512) void k_fit(
    const _Float16* __restrict__ featf, const _Float16* __restrict__ W0ht,
    const _Float16* __restrict__ W1ht,
    const float* __restrict__ b0, const float* __restrict__ b1,
    const float* __restrict__ W2, const float* __restrict__ b2,
    const float* __restrict__ Ebias, const int* __restrict__ n1p,
    unsigned int* __restrict__ counter, float* __restrict__ slots,
    float* __restrict__ out)
{
    __shared__ float s_red[4][2][8][64];               // 16 KB K-quarter partials
    __shared__ __align__(16) _Float16 s_hd[8][128];    // 2 KB
    __shared__ float s_sum[8][32];                     // 1 KB

    const int tid = threadIdx.x;
    const int lane = tid & 63, w = tid >> 6;
    const int kq = w >> 1, ch = w & 1;
    const int l15 = lane & 15, lk = lane >> 4;
    const int row8 = l15 & 7;                          // atom slot (rows dup'd)
    const int n0 = blockIdx.x * 8;
    const int ia = (n0 >= *n1p) ? 1 : 0;
    const f4 zf4 = {0.0f, 0.0f, 0.0f, 0.0f};

    // ---- layer 0: rows = 8 atoms (dup to 16), wave=(ch: 64 cols, kq: K=256)
    const _Float16* Ap = featf + (size_t)(n0 + row8) * 1024 + kq * 256;
    const _Float16* B0 = W0ht + (size_t)ia * 131072 + kq * 256;
    f4 acc[4] = {zf4, zf4, zf4, zf4};
    #pragma unroll
    for (int ks = 0; ks < 8; ks++) {
        h8 a = *(const h8*)(Ap + ks * 32 + 8 * lk);
        #pragma unroll
        for (int nt = 0; nt < 4; nt++) {
            const int c = ch * 64 + nt * 16 + l15;
            h8 b = *(const h8*)(B0 + (size_t)c * 1024 + ks * 32 + 8 * lk);
            acc[nt] = __builtin_amdgcn_mfma_f32_16x16x32_f16(a, b, acc[nt], 0, 0, 0);
        }
    }
    if (lk < 2) {     // rows 0-7 only
        #pragma unroll
        for (int nt = 0; nt < 4; nt++)
            #pragma unroll
            for (int r = 0; r < 4; r++)
                s_red[kq][ch][4 * lk + r][nt * 16 + l15] = acc[nt][r];
    }
    __syncthreads();

    // ---- reduce over kq + bias + tanh -> s_hd (f16, unit-swizzled) ----
    if (tid < 256) {
        const int row = tid >> 5, c0 = (tid & 31) * 4;
        const int chh = c0 >> 6, cl = c0 & 63;
        f4 v = *(const f4*)&s_red[0][chh][row][cl];
        v += *(const f4*)&s_red[1][chh][row][cl];
        v += *(const f4*)&s_red[2][chh][row][cl];
        v += *(const f4*)&s_red[3][chh][row][cl];
        #pragma unroll
        for (int q = 0; q < 4; q++) {
            int c = c0 + q;
            float h = fast_tanh(v[q] + b0[ia * 128 + c]);
            s_hd[row][((((c >> 3) ^ row) & 15) << 3) + (c & 7)] = (_Float16)h;
        }
    }
    __syncthreads();

    // ---- layer 1: wave=(ch: 64 cols, kq: K=32) ----
    f4 acc1[4] = {zf4, zf4, zf4, zf4};
    {
        h8 a = *(const h8*)&s_hd[row8][(((4 * kq + lk) ^ row8) & 15) << 3];
        const _Float16* B1 = W1ht + (size_t)ia * 16384 + kq * 32;
        #pragma unroll
        for (int nt = 0; nt < 4; nt++) {
            const int c = ch * 64 + nt * 16 + l15;
            h8 b = *(const h8*)(B1 + (size_t)c * 128 + 8 * lk);
            acc1[nt] = __builtin_amdgcn_mfma_f32_16x16x32_f16(a, b, zf4, 0, 0, 0);
        }
    }
    if (lk < 2) {
        #pragma unroll
        for (int nt = 0; nt < 4; nt++)
            #pragma unroll
            for (int r = 0; r < 4; r++)
                s_red[kq][ch][4 * lk + r][nt * 16 + l15] = acc1[nt][r];
    }
    __syncthreads();

    // ---- final: reduce + bias + tanh, x W2, deterministic block sums ----
    if (tid < 256) {
        const int row = tid >> 5, c0 = (tid & 31) * 4;
        const int chh = c0 >> 6, cl = c0 & 63;
        f4 v = *(const f4*)&s_red[0][chh][row][cl];
        v += *(const f4*)&s_red[1][chh][row][cl];
        v += *(const f4*)&s_red[2][chh][row][cl];
        v += *(const f4*)&s_red[3][chh][row][cl];
        float pv = 0.0f;
        #pragma unroll
        for (int q = 0; q < 4; q++) {
            int c = c0 + q;
            pv += fast_tanh(v[q] + b1[ia * 128 + c]) * W2[ia * 128 + c];
        }
        s_sum[row][tid & 31] = pv;
    }
    __syncthreads();
    if (w == 0) {
        const int row = lane >> 3, g = lane & 7;
        float s = 0.0f;
        #pragma unroll
        for (int i = 0; i < 4; i++) s += s_sum[row][4 * g + i];
        s += __shfl_xor(s, 1);  s += __shfl_xor(s, 2);   // across g
        s += __shfl_xor(s, 4);
        s += __shfl_xor(s, 8);  s += __shfl_xor(s, 16);  // across rows
        s += __shfl_xor(s, 32);
        if (lane == 0) {
            float e = s + 8.0f * (b2[ia] + Ebias[ia]);
            slots[blockIdx.x] = e;
            __threadfence();
            unsigned int old = atomicAdd(counter, 1u);
            if (old == 127u) {
                __threadfence();
                float tot = 0.0f;
                for (int i = 0; i < 128; i++)
                    tot += __hip_atomic_load(&slots[i], __ATOMIC_RELAXED, __HIP_MEMORY_SCOPE_AGENT);
                out[0] = tot;
            }
        }
    }
}

extern "C" void kernel_launch(void* const* d_in, const int* in_sizes, int n_in,
                              void* d_out, int out_size, void* d_ws, size_t ws_size,
                              hipStream_t stream) {
    const float* coord   = (const float*)d_in[0];
    const float* box     = (const float*)d_in[1];
    const float* srmean  = (const float*)d_in[2];
    const float* srstd   = (const float*)d_in[3];
    const float* xrsrstd = (const float*)d_in[4];
    const float* Gbias   = (const float*)d_in[5];
    const float* Ebias   = (const float*)d_in[6];
    const float* eW0     = (const float*)d_in[7];
    const float* eb0     = (const float*)d_in[8];
    const float* eW1     = (const float*)d_in[9];
    const float* eb1     = (const float*)d_in[10];
    const float* eW2     = (const float*)d_in[11];
    const float* eb2     = (const float*)d_in[12];
    const float* fW0     = (const float*)d_in[13];
    const float* fb0     = (const float*)d_in[14];
    const float* fW1     = (const float*)d_in[15];
    const float* fb1     = (const float*)d_in[16];
    const float* fW2     = (const float*)d_in[17];
    const float* fb2     = (const float*)d_in[18];
    const int*   n1p     = (const int*)d_in[19];

    const int N = in_sizes[0] / 3;          // 1024
    h2v*      featbuf = (h2v*)d_ws;                                       // 2 MB
    _Float16* W0ht = (_Float16*)((char*)d_ws + (size_t)2 * 1024 * 1024);  // 512 KB
    _Float16* W1ht = W0ht + 2 * 131072;                                   // 64 KB
    char* tail = (char*)d_ws + (size_t)(2 * 1024 + 512 + 64) * 1024;
    unsigned int* counter = (unsigned int*)tail;
    float*        slots   = (float*)(tail + 64);

    k_embed<<<N / 2 + NPREP, 256, 0, stream>>>(coord, box, srmean, srstd, xrsrstd,
                                               Gbias, eW0, eb0, eW1, eb1, eW2, eb2,
                                               n1p, fW0, fW1, featbuf, W0ht, W1ht,
                                               counter, N);
    k_fit<<<N / 8, 512, 0, stream>>>((const _Float16*)featbuf, W0ht, W1ht,
                                     fb0, fb1, fW2, fb2, Ebias, n1p,
                                     counter, slots, (float*)d_out);
}

// Round 14
// 39.588 us; speedup vs baseline: 3.0645x; 1.1645x over previous
//
#include <hip/hip_runtime.h>

#define RCUT 6.0f

typedef _Float16 h2v __attribute__((ext_vector_type(2)));
typedef _Float16 h8  __attribute__((ext_vector_type(8)));
typedef float    f4  __attribute__((ext_vector_type(4)));

__device__ __forceinline__ float fast_tanh(float x) {
    float e = __expf(2.0f * x);              // inf for large x -> tanh=1
    return 1.0f - 2.0f * __builtin_amdgcn_rcpf(e + 1.0f);
}

__device__ __forceinline__ h2v pkh(float a, float b) {
#if __has_builtin(__builtin_amdgcn_cvt_pkrtz)
    union { __fp16 __attribute__((ext_vector_type(2))) r; h2v h; } u;
    u.r = __builtin_amdgcn_cvt_pkrtz(a, b);
    return u.h;
#else
    h2v r; r.x = (_Float16)a; r.y = (_Float16)b; return r;
#endif
}

// ---- Kernel 1: 1 atom/block, barrier-free tile loop, in-register stage-2 ---
// Blocks [0, N): atoms. Blocks [N, N+288): fit-weight transpose prep.
__global__ __launch_bounds__(256, 4) void k_embed(
    const float* __restrict__ coord, const float* __restrict__ box,
    const float* __restrict__ srmean, const float* __restrict__ srstd,
    const float* __restrict__ xrsrstd, const float* __restrict__ Gbias,
    const float* __restrict__ eW0, const float* __restrict__ eb0,
    const float* __restrict__ eW1, const float* __restrict__ eb1,
    const float* __restrict__ eW2, const float* __restrict__ eb2,
    const int* __restrict__ n1p,
    const float* __restrict__ fW0, const float* __restrict__ fW1,
    h2v* __restrict__ feat, _Float16* __restrict__ W0ht,
    _Float16* __restrict__ W1ht, unsigned int* __restrict__ counter, int N)
{
    const int tid = threadIdx.x;

    __shared__ float s_w0[2][16], s_b0[2][16];
    __shared__ __align__(16) _Float16 s_srn[512];       // 1 KB
    __shared__ __align__(16) _Float16 s_cf[4][512];     // 4 KB
    __shared__ __align__(16) _Float16 s_h1[128][32];    // 8 KB (XOR-swz, wave-private rows)
    __shared__ unsigned short s_nbr[512];               // 1 KB
    __shared__ float s_g[4][4][64];                     // 4 KB per-wave partials
    __shared__ float s_g4[256];                         // 1 KB
    __shared__ __align__(16) _Float16 w1t[2][32][24];   // 3 KB
    __shared__ __align__(16) _Float16 w2t[2][64][40];   // 10 KB
    __shared__ int s_wcnt[4];

    // ================= prep path (blocks at grid end) ========================
    if (blockIdx.x >= (unsigned)N) {
        const int b = blockIdx.x - N;
        if (b == 0 && tid == 0) *counter = 0u;
        float (*s_t)[33] = reinterpret_cast<float(*)[33]>(&s_h1[0][0]);  // 4.2KB scratch
        if (b < 256) {
            int type = b >> 7, tb = b & 127;
            int ki = tb >> 2, ci = tb & 3;
            const float* src = fW0 + (size_t)type * 131072;
            int c = tid & 31, r0 = (tid >> 5) * 4;
            #pragma unroll
            for (int q = 0; q < 4; q++)
                s_t[r0 + q][c] = src[(size_t)(ki * 32 + r0 + q) * 128 + ci * 32 + c];
            __syncthreads();
            _Float16* dst = W0ht + (size_t)type * 131072;
            int kk = tid & 31, c0 = (tid >> 5) * 4;
            #pragma unroll
            for (int q = 0; q < 4; q++)
                dst[(size_t)(ci * 32 + c0 + q) * 1024 + ki * 32 + kk] = (_Float16)s_t[kk][c0 + q];
        } else {
            int b2v = b - 256, type = b2v >> 4, tb = b2v & 15;
            int ki = tb >> 2, ci = tb & 3;
            const float* src = fW1 + (size_t)type * 16384;
            int c = tid & 31, r0 = (tid >> 5) * 4;
            #pragma unroll
            for (int q = 0; q < 4; q++)
                s_t[r0 + q][c] = src[(size_t)(ki * 32 + r0 + q) * 128 + ci * 32 + c];
            __syncthreads();
            _Float16* dst = W1ht + (size_t)type * 16384;
            int kk = tid & 31, c0 = (tid >> 5) * 4;
            #pragma unroll
            for (int q = 0; q < 4; q++)
                dst[(size_t)(ci * 32 + c0 + q) * 128 + ki * 32 + kk] = (_Float16)s_t[kk][c0 + q];
        }
        return;
    }

    // ================= main path: one atom =================
    const int n  = blockIdx.x;
    const int n1 = *n1p;
    const int ti = (n >= n1) ? 1 : 0;
    const int wid = tid >> 6, lane = tid & 63;
    const int l15 = lane & 15, lk = lane >> 4;

    // ---- coalesced weight staging into LDS ----
    for (int t = tid; t < 32; t += 256) { int j = t >> 4, f = t & 15;
        s_w0[j][f] = eW0[(2 * ti + j) * 16 + f];
        s_b0[j][f] = eb0[(2 * ti + j) * 16 + f]; }
    for (int idx = tid; idx < 1024; idx += 256) {        // W1: [j][g(c)][f(k)]
        int j = idx >> 9, r = idx & 511, f = r >> 5, g = r & 31;
        w1t[j][g][f] = (_Float16)eW1[(2 * ti + j) * 512 + f * 32 + g];
    }
    for (int idx = tid; idx < 4096; idx += 256) {        // W2: [j][c][g(k)]
        int j = idx >> 11, r = idx & 2047, g = r >> 6, c = r & 63;
        w2t[j][c][g] = (_Float16)eW2[(2 * ti + j) * 2048 + g * 64 + c];
    }
    float b1r[2][2], b2r[2][4];
    #pragma unroll
    for (int j = 0; j < 2; j++) {
        #pragma unroll
        for (int q = 0; q < 2; q++) b1r[j][q] = eb1[(2 * ti + j) * 32 + 16 * q + l15];
        #pragma unroll
        for (int q = 0; q < 4; q++) b2r[j][q] = eb2[(2 * ti + j) * 64 + 16 * q + l15];
    }

    const float Lx = box[0], Ly = box[4], Lz = box[8];
    const float iLx = 1.0f / Lx, iLy = 1.0f / Ly, iLz = 1.0f / Lz;
    const float xn = coord[n], yn = coord[N + n], zn = coord[2 * N + n];
    const float srm  = srmean[ti];
    const float isrs = 1.0f / srstd[ti];
    const float ixrs = 1.0f / xrsrstd[ti];

    // ---- scan pass 1: ballots ----
    unsigned long long bal[4];
    {
        int wc = 0;
        const int mystart = wid * 256;
        #pragma unroll
        for (int r = 0; r < 4; r++) {
            int m = mystart + r * 64 + lane;
            float dx = coord[m] - xn;         dx -= Lx * rintf(dx * iLx);
            float dy = coord[N + m] - yn;     dy -= Ly * rintf(dy * iLy);
            float dz = coord[2 * N + m] - zn; dz -= Lz * rintf(dz * iLz);
            float r2 = dx * dx + dy * dy + dz * dz;
            bool pred = (r2 < RCUT * RCUT) && (m != n);
            bal[r] = __ballot(pred);
            wc += (int)__popcll(bal[r]);
        }
        if (lane == 0) s_wcnt[wid] = wc;
    }
    __syncthreads();
    int cnt = s_wcnt[0] + s_wcnt[1] + s_wcnt[2] + s_wcnt[3];
    if (cnt > 512) cnt = 512;
    // ---- scan pass 2: recompute geometry, write coefs (f16) ----
    {
        int base = 0;
        for (int w = 0; w < wid; w++) base += s_wcnt[w];
        const unsigned long long lt = (1ull << lane) - 1ull;
        const int mystart = wid * 256;
        #pragma unroll
        for (int r = 0; r < 4; r++) {
            int m = mystart + r * 64 + lane;
            if ((bal[r] >> lane) & 1ull) {
                int pos = base + (int)__popcll(bal[r] & lt);
                if (pos < 512) {
                    float dx = coord[m] - xn;         dx -= Lx * rintf(dx * iLx);
                    float dy = coord[N + m] - yn;     dy -= Ly * rintf(dy * iLy);
                    float dz = coord[2 * N + m] - zn; dz -= Lz * rintf(dz * iLz);
                    float r2 = dx * dx + dy * dy + dz * dz;
                    float rr = sqrtf(r2);
                    float rinv = __builtin_amdgcn_rcpf(rr);
                    float u  = rr * (1.0f / RCUT);
                    float u3 = u * u * u;
                    float sw_ = ((-6.0f * u + 15.0f) * u - 10.0f) * u3 + 1.0f;
                    float sr  = sw_ * rinv;
                    float crs = sr * rinv * ixrs + 1e-15f;
                    s_srn[pos]   = (_Float16)((sr - srm) * isrs);
                    s_cf[0][pos] = (_Float16)(sr * isrs);
                    s_cf[1][pos] = (_Float16)(crs * dx);
                    s_cf[2][pos] = (_Float16)(crs * dy);
                    s_cf[3][pos] = (_Float16)(crs * dz);
                    s_nbr[pos]   = (unsigned short)m;
                }
            }
            base += (int)__popcll(bal[r]);
        }
    }
    __syncthreads();
    const int ntiles = (cnt + 127) >> 7;
    for (int i = cnt + tid; i < ntiles * 128; i += 256) {
        s_srn[i] = (_Float16)0.0f; s_nbr[i] = 0;
        s_cf[0][i] = (_Float16)0.0f; s_cf[1][i] = (_Float16)0.0f;
        s_cf[2][i] = (_Float16)0.0f; s_cf[3][i] = (_Float16)0.0f;
    }
    __syncthreads();

    const f4 zf4 = {0.0f, 0.0f, 0.0f, 0.0f};
    float gk[4][4] = {};   // [k][nt] in-register G partials (f32)

    // ---- BARRIER-FREE tile loop: each wave owns rows 32*wid..32*wid+31 ----
    for (int t = 0; t < ntiles; t++) {
        const int t128 = t << 7;
        #pragma unroll
        for (int mt2 = 0; mt2 < 2; mt2++) {
            const int mt = 2 * wid + mt2;
            const int row = 16 * mt + l15;
            const int rp = t128 + row;
            float srn = (float)s_srn[rp];
            int jr = (s_nbr[rp] >= n1) ? 1 : 0;
            h8 a = {};
            if (lk < 2) {
                const float* wp = &s_w0[jr][8 * lk];
                const float* bp = &s_b0[jr][8 * lk];
                #pragma unroll
                for (int q = 0; q < 8; q++)
                    a[q] = (_Float16)fast_tanh(fmaf(srn, wp[q], bp[q]));
            }
            int j_r[4];
            #pragma unroll
            for (int r = 0; r < 4; r++)
                j_r[r] = (s_nbr[t128 + 16 * mt + 4 * lk + r] >= n1) ? 1 : 0;

            // W1: h1 rows (wave-private LDS)
            #pragma unroll
            for (int nt1 = 0; nt1 < 2; nt1++) {
                const int c = 16 * nt1 + l15;
                h8 b0f = {}, b1f = {};
                if (lk < 2) {
                    b0f = *(const h8*)&w1t[0][c][8 * lk];
                    b1f = *(const h8*)&w1t[1][c][8 * lk];
                }
                f4 d0 = __builtin_amdgcn_mfma_f32_16x16x32_f16(a, b0f, zf4, 0, 0, 0);
                f4 d1 = __builtin_amdgcn_mfma_f32_16x16x32_f16(a, b1f, zf4, 0, 0, 0);
                #pragma unroll
                for (int r = 0; r < 4; r++) {
                    int gp = 16 * mt + 4 * lk + r;
                    float hv = fast_tanh((j_r[r] ? d1[r] : d0[r]) + (j_r[r] ? b1r[1][nt1] : b1r[0][nt1]));
                    int e = 16 * nt1 + l15;
                    s_h1[gp][(((e >> 3) ^ ((gp >> 1) & 3)) << 3) + (e & 7)] = (_Float16)hv;
                }
            }
            asm volatile("" ::: "memory");   // same-wave LDS: W2 reads after W1 writes

            // W2 + in-register stage-2
            h8 a2 = *(const h8*)&s_h1[row][((lk ^ ((row >> 1) & 3)) << 3)];
            float cfv[4][4];
            #pragma unroll
            for (int k = 0; k < 4; k++) {
                #pragma unroll
                for (int r = 0; r < 4; r++)
                    cfv[k][r] = (float)s_cf[k][t128 + 16 * mt + 4 * lk + r];
            }
            #pragma unroll
            for (int nt = 0; nt < 4; nt++) {
                h8 w20 = *(const h8*)&w2t[0][16 * nt + l15][8 * lk];
                h8 w21 = *(const h8*)&w2t[1][16 * nt + l15][8 * lk];
                f4 e0 = __builtin_amdgcn_mfma_f32_16x16x32_f16(a2, w20, zf4, 0, 0, 0);
                f4 e1 = __builtin_amdgcn_mfma_f32_16x16x32_f16(a2, w21, zf4, 0, 0, 0);
                #pragma unroll
                for (int r = 0; r < 4; r++) {
                    float ev = fast_tanh((j_r[r] ? e1[r] : e0[r]) + (j_r[r] ? b2r[1][nt] : b2r[0][nt]));
                    #pragma unroll
                    for (int k = 0; k < 4; k++)
                        gk[k][nt] = fmaf(cfv[k][r], ev, gk[k][nt]);
                }
            }
        }
    }

    // ---- reduce: lk groups via shuffle, then waves via LDS ----
    #pragma unroll
    for (int k = 0; k < 4; k++) {
        #pragma unroll
        for (int nt = 0; nt < 4; nt++) {
            float v = gk[k][nt];
            v += __shfl_xor(v, 16);
            v += __shfl_xor(v, 32);
            if (lane < 16) s_g[wid][k][nt * 16 + lane] = v;
        }
    }
    __syncthreads();
    {
        int k = tid >> 6, c = tid & 63;
        float g = (s_g[0][k][c] + s_g[1][k][c]) + (s_g[2][k][c] + s_g[3][k][c]);
        g *= (1.0f / 64.0f);
        if (k == 0) g += Gbias[c];
        s_g4[k * 64 + c] = g;
    }
    __syncthreads();

    // ---- Feat epilogue (single atom) ----
    {
        h2v* outp = feat + (size_t)n * 512;
        #pragma unroll
        for (int q = 0; q < 2; q++) {
            int o2 = tid + 256 * q;
            int a = o2 >> 5, c = (2 * o2) & 63;
            float ga0 = s_g4[a],       ga1 = s_g4[64 + a];
            float ga2 = s_g4[128 + a], ga3 = s_g4[192 + a];
            float s0 = ga0 * s_g4[c];
            s0 = fmaf(ga1, s_g4[64 + c],  s0);
            s0 = fmaf(ga2, s_g4[128 + c], s0);
            s0 = fmaf(ga3, s_g4[192 + c], s0);
            float s1 = ga0 * s_g4[c + 1];
            s1 = fmaf(ga1, s_g4[64 + c + 1],  s1);
            s1 = fmaf(ga2, s_g4[128 + c + 1], s1);
            s1 = fmaf(ga3, s_g4[192 + c + 1], s1);
            outp[o2] = pkh(s0, s1);
        }
    }
}

// ---- Kernel 2: fit net, 64 blocks x 16 atoms, direct-from-L2 fragments ----
__global__ __launch_bounds__(512) void k_fit(
    const _Float16* __restrict__ featf, const _Float16* __restrict__ W0ht,
    const _Float16* __restrict__ W1ht,
    const float* __restrict__ b0, const float* __restrict__ b1,
    const float* __restrict__ W2, const float* __restrict__ b2,
    const float* __restrict__ Ebias, const int* __restrict__ n1p,
    unsigned int* __restrict__ counter, float* __restrict__ slots,
    float* __restrict__ out)
{
    __shared__ float s_red[4][2][16][64];
    __shared__ __align__(16) _Float16 s_hd[16][128];
    __shared__ float s_sum[16][32];

    const int tid = threadIdx.x;
    const int lane = tid & 63, w = tid >> 6;
    const int kq = w >> 1, ch = w & 1;
    const int l15 = lane & 15, lk = lane >> 4;
    const int n0 = blockIdx.x * 16;
    const int ia = (n0 >= *n1p) ? 1 : 0;
    const f4 zf4 = {0.0f, 0.0f, 0.0f, 0.0f};

    const _Float16* Ap = featf + (size_t)(n0 + l15) * 1024 + kq * 256;
    const _Float16* B0 = W0ht + (size_t)ia * 131072 + kq * 256;
    f4 acc[4] = {zf4, zf4, zf4, zf4};
    #pragma unroll
    for (int ks = 0; ks < 8; ks++) {
        h8 a = *(const h8*)(Ap + ks * 32 + 8 * lk);
        #pragma unroll
        for (int nt = 0; nt < 4; nt++) {
            const int c = ch * 64 + nt * 16 + l15;
            h8 b = *(const h8*)(B0 + (size_t)c * 1024 + ks * 32 + 8 * lk);
            acc[nt] = __builtin_amdgcn_mfma_f32_16x16x32_f16(a, b, acc[nt], 0, 0, 0);
        }
    }
    #pragma unroll
    for (int nt = 0; nt < 4; nt++)
        #pragma unroll
        for (int r = 0; r < 4; r++)
            s_red[kq][ch][4 * lk + r][nt * 16 + l15] = acc[nt][r];
    __syncthreads();

    {
        const int row = tid >> 5, c0 = (tid & 31) * 4;
        const int chh = c0 >> 6, cl = c0 & 63;
        f4 v = *(const f4*)&s_red[0][chh][row][cl];
        v += *(const f4*)&s_red[1][chh][row][cl];
        v += *(const f4*)&s_red[2][chh][row][cl];
        v += *(const f4*)&s_red[3][chh][row][cl];
        #pragma unroll
        for (int q = 0; q < 4; q++) {
            int c = c0 + q;
            float h = fast_tanh(v[q] + b0[ia * 128 + c]);
            s_hd[row][(((c >> 3) ^ row) << 3) + (c & 7)] = (_Float16)h;
        }
    }
    __syncthreads();

    f4 acc1[4] = {zf4, zf4, zf4, zf4};
    {
        h8 a = *(const h8*)&s_hd[l15][(((4 * kq + lk) ^ l15) & 15) << 3];
        const _Float16* B1 = W1ht + (size_t)ia * 16384 + kq * 32;
        #pragma unroll
        for (int nt = 0; nt < 4; nt++) {
            const int c = ch * 64 + nt * 16 + l15;
            h8 b = *(const h8*)(B1 + (size_t)c * 128 + 8 * lk);
            acc1[nt] = __builtin_amdgcn_mfma_f32_16x16x32_f16(a, b, zf4, 0, 0, 0);
        }
    }
    #pragma unroll
    for (int nt = 0; nt < 4; nt++)
        #pragma unroll
        for (int r = 0; r < 4; r++)
            s_red[kq][ch][4 * lk + r][nt * 16 + l15] = acc1[nt][r];
    __syncthreads();

    {
        const int row = tid >> 5, c0 = (tid & 31) * 4;
        const int chh = c0 >> 6, cl = c0 & 63;
        f4 v = *(const f4*)&s_red[0][chh][row][cl];
        v += *(const f4*)&s_red[1][chh][row][cl];
        v += *(const f4*)&s_red[2][chh][row][cl];
        v += *(const f4*)&s_red[3][chh][row][cl];
        float pv = 0.0f;
        #pragma unroll
        for (int q = 0; q < 4; q++) {
            int c = c0 + q;
            pv += fast_tanh(v[q] + b1[ia * 128 + c]) * W2[ia * 128 + c];
        }
        s_sum[row][tid & 31] = pv;
    }
    __syncthreads();
    if (w == 0) {
        const int row = lane >> 2, g = lane & 3;
        float s = 0.0f;
        #pragma unroll
        for (int i = 0; i < 8; i++) s += s_sum[row][8 * g + i];
        s += __shfl_xor(s, 1);  s += __shfl_xor(s, 2);
        s += __shfl_xor(s, 4);  s += __shfl_xor(s, 8);
        s += __shfl_xor(s, 16); s += __shfl_xor(s, 32);
        if (lane == 0) {
            float e = s + 16.0f * (b2[ia] + Ebias[ia]);
            slots[blockIdx.x] = e;
            __threadfence();
            unsigned int old = atomicAdd(counter, 1u);
            if (old == 63u) {
                __threadfence();
                float tot = 0.0f;
                for (int i = 0; i < 64; i++)
                    tot += __hip_atomic_load(&slots[i], __ATOMIC_RELAXED, __HIP_MEMORY_SCOPE_AGENT);
                out[0] = tot;
            }
        }
    }
}

extern "C" void kernel_launch(void* const* d_in, const int* in_sizes, int n_in,
                              void* d_out, int out_size, void* d_ws, size_t ws_size,
                              hipStream_t stream) {
    const float* coord   = (const float*)d_in[0];
    const float* box     = (const float*)d_in[1];
    const float* srmean  = (const float*)d_in[2];
    const float* srstd   = (const float*)d_in[3];
    const float* xrsrstd = (const float*)d_in[4];
    const float* Gbias   = (const float*)d_in[5];
    const float* Ebias   = (const float*)d_in[6];
    const float* eW0     = (const float*)d_in[7];
    const float* eb0     = (const float*)d_in[8];
    const float* eW1     = (const float*)d_in[9];
    const float* eb1     = (const float*)d_in[10];
    const float* eW2     = (const float*)d_in[11];
    const float* eb2     = (const float*)d_in[12];
    const float* fW0     = (const float*)d_in[13];
    const float* fb0     = (const float*)d_in[14];
    const float* fW1     = (const float*)d_in[15];
    const float* fb1     = (const float*)d_in[16];
    const float* fW2     = (const float*)d_in[17];
    const float* fb2     = (const float*)d_in[18];
    const int*   n1p     = (const int*)d_in[19];

    const int N = in_sizes[0] / 3;          // 1024
    h2v*      featbuf = (h2v*)d_ws;                                       // 2 MB
    _Float16* W0ht = (_Float16*)((char*)d_ws + (size_t)2 * 1024 * 1024);  // 512 KB
    _Float16* W1ht = W0ht + 2 * 131072;                                   // 64 KB
    char* tail = (char*)d_ws + (size_t)(2 * 1024 + 512 + 64) * 1024;
    unsigned int* counter = (unsigned int*)tail;
    float*        slots   = (float*)(tail + 64);

    k_embed<<<N + 288, 256, 0, stream>>>(coord, box, srmean, srstd, xrsrstd,
                                         Gbias, eW0, eb0, eW1, eb1, eW2, eb2,
                                         n1p, fW0, fW1, featbuf, W0ht, W1ht,
                                         counter, N);
    k_fit<<<N / 16, 512, 0, stream>>>((const _Float16*)featbuf, W0ht, W1ht,
                                      fb0, fb1, fW2, fb2, Ebias, n1p,
                                      counter, slots, (float*)d_out);
}